// Round 2
// baseline (472.417 us; speedup 1.0000x reference)
//
#include <hip/hip_runtime.h>
#include <math.h>

// DeepOHeat_ST: 4 trunk MLPs + branch MLP -> rank-64 CP reconstruction,
// recast as GEMM: out[(b,i,j),(k,l)] = sum_z S[m,z]*T[z,n]
//   S[m,z] = t0[i,z]*t1[j,z]*br[b,z]   (m = b*4096 + i*64 + j, M=32768)
//   T[z,n] = t2[k,z]*t3[l,z]           (n = k*32 + l,          N=2048, K=64)
// S,T built in bf16 inside the GEMM kernel's LDS staging; MFMA 16x16x32 bf16.
//
// ws layout (floats, row-major [row][z]):
//   t0RM 64x64 @ 0, t1RM 64x64 @ 4096, t2RM 64x64 @ 8192,
//   t3RM 32x64 @ 12288, brRM 8x64 @ 14336

typedef float float4v __attribute__((ext_vector_type(4)));
typedef short short8 __attribute__((ext_vector_type(8)));

__device__ inline unsigned short f2bf(float f) {
    union { float f; unsigned u; } c; c.f = f;
    unsigned u = c.u;
    unsigned r = (u + 0x7FFFu + ((u >> 16) & 1u)) >> 16;   // RNE
    return (unsigned short)r;
}

// ---------------- net_eval: wave-cooperative MLP ----------------
// One block (256 thr = 4 waves) per row. Each output j: one wave reads the
// 1KB weight row coalesced (16B/lane), partial dot, butterfly reduce.

template<int IN, int OUT, bool ACT>
__device__ inline void layer(const float* __restrict__ W,
                             const float* __restrict__ Bv,
                             const float* __restrict__ xin,   // LDS, IN floats
                             float* __restrict__ yout,        // LDS, OUT floats
                             int t)
{
    const int lane = t & 63;
    const int w    = t >> 6;
    constexpr int C   = IN / 64;    // floats per lane (2 or 4)
    constexpr int JPW = OUT / 4;    // outputs per wave

    float xr[C];
    #pragma unroll
    for (int c = 0; c < C; ++c) xr[c] = xin[lane * C + c];

    #pragma unroll 2
    for (int jj = 0; jj < JPW; ++jj) {
        int j = w * JPW + jj;
        float s;
        if (C == 4) {
            float4 wv = ((const float4*)(W + (size_t)j * IN))[lane];
            s = wv.x * xr[0] + wv.y * xr[1] + wv.z * xr[2] + wv.w * xr[3];
        } else {
            float2 wv = ((const float2*)(W + (size_t)j * IN))[lane];
            s = wv.x * xr[0] + wv.y * xr[1];
        }
        #pragma unroll
        for (int m = 32; m >= 1; m >>= 1) s += __shfl_xor(s, m, 64);
        s += Bv[j];
        if (ACT) s = s / (1.0f + expf(-s));
        if (lane == 0) yout[j] = s;
    }
}

__global__ __launch_bounds__(256) void net_eval(
    const float* __restrict__ x1, const float* __restrict__ x2,
    const float* __restrict__ x3, const float* __restrict__ x4,
    const float* __restrict__ f,  const float* __restrict__ Bm,
    const float* __restrict__ tW0, const float* __restrict__ tb0,
    const float* __restrict__ tW1, const float* __restrict__ tb1,
    const float* __restrict__ tW2, const float* __restrict__ tb2,
    const float* __restrict__ tW3, const float* __restrict__ tb3,
    const float* __restrict__ bW0, const float* __restrict__ bb0,
    const float* __restrict__ bW1, const float* __restrict__ bb1,
    const float* __restrict__ bW2, const float* __restrict__ bb2,
    const float* __restrict__ bW3, const float* __restrict__ bb3,
    float* __restrict__ ws)
{
    __shared__ float buf0[256];
    __shared__ float buf1[256];
    const int t   = threadIdx.x;
    const int bid = blockIdx.x;

    int net, row;
    if (bid < 192)      { net = bid >> 6; row = bid & 63; }
    else if (bid < 224) { net = 3;        row = bid - 192; }
    else                { net = 4;        row = bid - 224; }

    const float *W0, *B0v, *W1, *B1v, *W2, *B2v, *W3, *B3v;
    if (net < 4) {
        W0 = tW0 + (size_t)net * 256 * 128; B0v = tb0 + net * 256;
        W1 = tW1 + (size_t)net * 256 * 256; B1v = tb1 + net * 256;
        W2 = tW2 + (size_t)net * 256 * 256; B2v = tb2 + net * 256;
        W3 = tW3 + (size_t)net * 64 * 256;  B3v = tb3 + net * 64;
        const float* xp = (net == 0) ? x1 : (net == 1) ? x2 : (net == 2) ? x3 : x4;
        float xv = xp[row];
        if (t < 128) {
            float p = xv * Bm[t & 63];
            buf0[t] = (t < 64) ? cosf(p) : sinf(p);
        }
    } else {
        W0 = bW0; B0v = bb0; W1 = bW1; B1v = bb1;
        W2 = bW2; B2v = bb2; W3 = bW3; B3v = bb3;
        buf0[t] = f[(size_t)row * 256 + t];
    }
    __syncthreads();

    if (net < 4) layer<128, 256, true>(W0, B0v, buf0, buf1, t);
    else         layer<256, 256, true>(W0, B0v, buf0, buf1, t);
    __syncthreads();
    layer<256, 256, true>(W1, B1v, buf1, buf0, t);
    __syncthreads();
    layer<256, 256, true>(W2, B2v, buf0, buf1, t);
    __syncthreads();
    layer<256, 64, false>(W3, B3v, buf1, buf0, t);
    __syncthreads();

    if (t < 64) {
        int base;
        if      (net == 0) base = 0;
        else if (net == 1) base = 4096;
        else if (net == 2) base = 8192;
        else if (net == 3) base = 12288;
        else               base = 14336;
        ws[base + row * 64 + t] = buf0[t];
    }
}

// ---------------- cp_gemm: MFMA GEMM with fused S/T build ----------------
// Grid 4096 = mblk(256) x nblk(16). Block 256 thr = 4 waves (2x2 of 64x64).
// LDS: S-tile 128x64 bf16 (rows padded to 72), T-tile 128x64 bf16 (n-major).

#define PAD 72

__global__ __launch_bounds__(256) void cp_gemm(
    const float* __restrict__ ws, float* __restrict__ out)
{
    __shared__ __align__(16) unsigned short Ssh[128 * PAD];
    __shared__ __align__(16) unsigned short Tsh[128 * PAD];

    const int t    = threadIdx.x;
    const int bid  = blockIdx.x;
    const int mblk = bid >> 4;
    const int nblk = bid & 15;
    const int m0   = mblk * 128;
    const int n0   = nblk * 128;

    const float* t0p = ws;
    const float* t1p = ws + 4096;
    const float* t2p = ws + 8192;
    const float* t3p = ws + 12288;
    const float* brp = ws + 14336;

    // ---- build S-tile and T-tile in bf16 ----
    {
        const int z     = t & 63;
        const int rbase = t >> 6;
        #pragma unroll
        for (int it = 0; it < 32; ++it) {
            int r = rbase + it * 4;
            int m = m0 + r;
            int b = m >> 12, i = (m >> 6) & 63, j = m & 63;
            float v = t0p[i * 64 + z] * t1p[j * 64 + z] * brp[b * 64 + z];
            Ssh[r * PAD + z] = f2bf(v);
        }
        #pragma unroll
        for (int it = 0; it < 32; ++it) {
            int nr = rbase + it * 4;
            int n  = n0 + nr;
            int k  = n >> 5, l = n & 31;
            float v = t2p[k * 64 + z] * t3p[l * 64 + z];
            Tsh[nr * PAD + z] = f2bf(v);
        }
    }
    __syncthreads();

    // ---- MFMA: wave (wm,wn) computes 64x64 via 4x4 tiles of 16x16 ----
    const int w    = t >> 6;
    const int lane = t & 63;
    const int wm   = w >> 1;
    const int wn   = w & 1;
    const int l16  = lane & 15;
    const int quad = lane >> 4;

    float4v acc[4][4];
    #pragma unroll
    for (int mt = 0; mt < 4; ++mt)
        #pragma unroll
        for (int nt = 0; nt < 4; ++nt)
            acc[mt][nt] = (float4v){0.f, 0.f, 0.f, 0.f};

    #pragma unroll
    for (int ks = 0; ks < 2; ++ks) {
        short8 a[4], b[4];
        #pragma unroll
        for (int mt = 0; mt < 4; ++mt)
            a[mt] = *(const short8*)&Ssh[(wm * 64 + mt * 16 + l16) * PAD + ks * 32 + quad * 8];
        #pragma unroll
        for (int nt = 0; nt < 4; ++nt)
            b[nt] = *(const short8*)&Tsh[(wn * 64 + nt * 16 + l16) * PAD + ks * 32 + quad * 8];
        #pragma unroll
        for (int mt = 0; mt < 4; ++mt)
            #pragma unroll
            for (int nt = 0; nt < 4; ++nt)
                acc[mt][nt] = __builtin_amdgcn_mfma_f32_16x16x32_bf16(
                    a[mt], b[nt], acc[mt][nt], 0, 0, 0);
    }

    // ---- store: row = m0+wm*64+mt*16+quad*4+r, col = n0+wn*64+nt*16+l16 ----
    #pragma unroll
    for (int mt = 0; mt < 4; ++mt) {
        int mrow = m0 + wm * 64 + mt * 16 + quad * 4;
        #pragma unroll
        for (int nt = 0; nt < 4; ++nt) {
            int ncol = n0 + wn * 64 + nt * 16 + l16;
            float* op = out + (size_t)mrow * 2048 + ncol;
            #pragma unroll
            for (int r = 0; r < 4; ++r)
                op[(size_t)r * 2048] = acc[mt][nt][r];
        }
    }
}

extern "C" void kernel_launch(void* const* d_in, const int* in_sizes, int n_in,
                              void* d_out, int out_size, void* d_ws, size_t ws_size,
                              hipStream_t stream) {
    const float* x1  = (const float*)d_in[0];
    const float* x2  = (const float*)d_in[1];
    const float* x3  = (const float*)d_in[2];
    const float* x4  = (const float*)d_in[3];
    const float* f   = (const float*)d_in[4];
    const float* Bm  = (const float*)d_in[5];
    const float* tW0 = (const float*)d_in[6];
    const float* tb0 = (const float*)d_in[7];
    const float* tW1 = (const float*)d_in[8];
    const float* tb1 = (const float*)d_in[9];
    const float* tW2 = (const float*)d_in[10];
    const float* tb2 = (const float*)d_in[11];
    const float* tW3 = (const float*)d_in[12];
    const float* tb3 = (const float*)d_in[13];
    const float* bW0 = (const float*)d_in[14];
    const float* bb0 = (const float*)d_in[15];
    const float* bW1 = (const float*)d_in[16];
    const float* bb1 = (const float*)d_in[17];
    const float* bW2 = (const float*)d_in[18];
    const float* bb2 = (const float*)d_in[19];
    const float* bW3 = (const float*)d_in[20];
    const float* bb3 = (const float*)d_in[21];

    float* ws  = (float*)d_ws;
    float* out = (float*)d_out;

    hipLaunchKernelGGL(net_eval, dim3(232), dim3(256), 0, stream,
                       x1, x2, x3, x4, f, Bm,
                       tW0, tb0, tW1, tb1, tW2, tb2, tW3, tb3,
                       bW0, bb0, bW1, bb1, bW2, bb2, bW3, bb3, ws);
    hipLaunchKernelGGL(cp_gemm, dim3(4096), dim3(256), 0, stream, ws, out);
}